// Round 1
// baseline (2012.966 us; speedup 1.0000x reference)
//
#include <hip/hip_runtime.h>

#define NV 100000
#define NF 50000
#define NE 1000000
// D = 128 throughout

// -------------------- zero d_out (used as aggregation buffer) --------------------
__global__ __launch_bounds__(256) void zero_f4(float4* __restrict__ p, int n4) {
    int i = blockIdx.x * 256 + threadIdx.x;
    if (i < n4) p[i] = make_float4(0.f, 0.f, 0.f, 0.f);
}

// -------------------- C[M x 128] = A[M x 128] @ W[128 x 128] (+ bias) --------------------
// 64-row tile per block, 256 threads, each thread: 4 rows x 8 cols (two 4-col halves).
// K split into 2 tiles of 64. LDS ~50 KB -> 3 blocks/CU.
__global__ __launch_bounds__(256) void gemm_one(const float* __restrict__ A,
                                                const float* __restrict__ W,
                                                const float* __restrict__ bias,
                                                float* __restrict__ C, int M) {
    __shared__ float sA[64 * 68];    // stride 68: (4*row+k)%32 -> 2-way max (free)
    __shared__ float sW[64 * 128];   // (tx*4)%32 -> 2-way max (free)
    const int tid = threadIdx.x;
    const int tx = tid & 15;         // col group
    const int ty = tid >> 4;         // row group
    const int r0 = blockIdx.x * 64;

    float acc[4][8];
#pragma unroll
    for (int i = 0; i < 4; i++)
#pragma unroll
        for (int j = 0; j < 8; j++) acc[i][j] = 0.f;

    for (int kt = 0; kt < 2; ++kt) {
        const int k0 = kt * 64;
        // stage A tile (64 rows x 64 k), zero-fill OOB rows
#pragma unroll
        for (int i = 0; i < 4; i++) {
            int f = tid + i * 256;          // 1024 float4
            int r = f >> 4, c4 = f & 15;
            float4 v = make_float4(0.f, 0.f, 0.f, 0.f);
            if (r0 + r < M) v = *(const float4*)(A + (size_t)(r0 + r) * 128 + k0 + c4 * 4);
            *(float4*)(sA + r * 68 + c4 * 4) = v;
        }
        // stage W tile (64 k x 128 cols)
#pragma unroll
        for (int i = 0; i < 8; i++) {
            int f = tid + i * 256;          // 2048 float4
            int r = f >> 5, c4 = f & 31;
            *(float4*)(sW + r * 128 + c4 * 4) = *(const float4*)(W + (size_t)(k0 + r) * 128 + c4 * 4);
        }
        __syncthreads();
#pragma unroll 8
        for (int k = 0; k < 64; k++) {
            float a[4];
#pragma unroll
            for (int i = 0; i < 4; i++) a[i] = sA[(ty * 4 + i) * 68 + k];
            float wv[8];
            *(float4*)&wv[0] = *(const float4*)(sW + k * 128 + tx * 4);
            *(float4*)&wv[4] = *(const float4*)(sW + k * 128 + 64 + tx * 4);
#pragma unroll
            for (int i = 0; i < 4; i++)
#pragma unroll
                for (int j = 0; j < 8; j++) acc[i][j] += a[i] * wv[j];
        }
        __syncthreads();
    }

    float b[8] = {0.f, 0.f, 0.f, 0.f, 0.f, 0.f, 0.f, 0.f};
    if (bias) {
        *(float4*)&b[0] = *(const float4*)(bias + tx * 4);
        *(float4*)&b[4] = *(const float4*)(bias + 64 + tx * 4);
    }
#pragma unroll
    for (int i = 0; i < 4; i++) {
        int r = r0 + ty * 4 + i;
        if (r < M) {
            float4 o0 = make_float4(acc[i][0] + b[0], acc[i][1] + b[1], acc[i][2] + b[2], acc[i][3] + b[3]);
            float4 o1 = make_float4(acc[i][4] + b[4], acc[i][5] + b[5], acc[i][6] + b[6], acc[i][7] + b[7]);
            *(float4*)(C + (size_t)r * 128 + tx * 4) = o0;
            *(float4*)(C + (size_t)r * 128 + 64 + tx * 4) = o1;
        }
    }
}

// -------------------- per-edge: m = relu(u[v] + w[f]); atomic scatter into aggr[v] ------
// 32 lanes per edge, float4 per lane. Grid is exact: NE*32 threads.
__global__ __launch_bounds__(256) void edge_scatter(const float* __restrict__ u,
                                                    const float* __restrict__ w,
                                                    const int* __restrict__ vtf,
                                                    const int* __restrict__ ftv,
                                                    float* __restrict__ aggr) {
    int t = blockIdx.x * 256 + threadIdx.x;
    int e = t >> 5, l = t & 31;
    int v = vtf[e];
    int f = ftv[e];
    const float4 a = *(const float4*)(u + (size_t)v * 128 + l * 4);
    const float4 bb = *(const float4*)(w + (size_t)f * 128 + l * 4);
    float m0 = fmaxf(a.x + bb.x, 0.f);
    float m1 = fmaxf(a.y + bb.y, 0.f);
    float m2 = fmaxf(a.z + bb.z, 0.f);
    float m3 = fmaxf(a.w + bb.w, 0.f);
    float* dst = aggr + (size_t)v * 128 + l * 4;
    unsafeAtomicAdd(dst + 0, m0);   // global_atomic_add_f32 (no CAS loop)
    unsafeAtomicAdd(dst + 1, m1);
    unsafeAtomicAdd(dst + 2, m2);
    unsafeAtomicAdd(dst + 3, m3);
}

// -------------------- OUT = V + relu(V@W1 + OUT@W2 + bias), in-place over OUT ----------
__global__ __launch_bounds__(256) void gemm_final(const float* __restrict__ V,
                                                  const float* __restrict__ W1,
                                                  const float* __restrict__ W2,
                                                  const float* __restrict__ bias,
                                                  float* __restrict__ OUT, int M) {
    __shared__ float sA[64 * 68];
    __shared__ float sW[64 * 128];
    const int tid = threadIdx.x;
    const int tx = tid & 15;
    const int ty = tid >> 4;
    const int r0 = blockIdx.x * 64;

    float acc[4][8];
#pragma unroll
    for (int i = 0; i < 4; i++)
#pragma unroll
        for (int j = 0; j < 8; j++) acc[i][j] = 0.f;

    for (int kt = 0; kt < 4; ++kt) {
        const float* A = (kt < 2) ? V : OUT;     // OUT holds aggr_m here
        const float* W = (kt < 2) ? W1 : W2;
        const int k0 = (kt & 1) * 64;
#pragma unroll
        for (int i = 0; i < 4; i++) {
            int f = tid + i * 256;
            int r = f >> 4, c4 = f & 15;
            float4 v = make_float4(0.f, 0.f, 0.f, 0.f);
            if (r0 + r < M) v = *(const float4*)(A + (size_t)(r0 + r) * 128 + k0 + c4 * 4);
            *(float4*)(sA + r * 68 + c4 * 4) = v;
        }
#pragma unroll
        for (int i = 0; i < 8; i++) {
            int f = tid + i * 256;
            int r = f >> 5, c4 = f & 31;
            *(float4*)(sW + r * 128 + c4 * 4) = *(const float4*)(W + (size_t)(k0 + r) * 128 + c4 * 4);
        }
        __syncthreads();
#pragma unroll 8
        for (int k = 0; k < 64; k++) {
            float a[4];
#pragma unroll
            for (int i = 0; i < 4; i++) a[i] = sA[(ty * 4 + i) * 68 + k];
            float wv[8];
            *(float4*)&wv[0] = *(const float4*)(sW + k * 128 + tx * 4);
            *(float4*)&wv[4] = *(const float4*)(sW + k * 128 + 64 + tx * 4);
#pragma unroll
            for (int i = 0; i < 4; i++)
#pragma unroll
                for (int j = 0; j < 8; j++) acc[i][j] += a[i] * wv[j];
        }
        __syncthreads();
    }

    float b[8];
    *(float4*)&b[0] = *(const float4*)(bias + tx * 4);
    *(float4*)&b[4] = *(const float4*)(bias + 64 + tx * 4);
#pragma unroll
    for (int i = 0; i < 4; i++) {
        int r = r0 + ty * 4 + i;
        if (r < M) {
            float4 v0 = *(const float4*)(V + (size_t)r * 128 + tx * 4);
            float4 v1 = *(const float4*)(V + (size_t)r * 128 + 64 + tx * 4);
            float4 o0 = make_float4(v0.x + fmaxf(acc[i][0] + b[0], 0.f),
                                    v0.y + fmaxf(acc[i][1] + b[1], 0.f),
                                    v0.z + fmaxf(acc[i][2] + b[2], 0.f),
                                    v0.w + fmaxf(acc[i][3] + b[3], 0.f));
            float4 o1 = make_float4(v1.x + fmaxf(acc[i][4] + b[4], 0.f),
                                    v1.y + fmaxf(acc[i][5] + b[5], 0.f),
                                    v1.z + fmaxf(acc[i][6] + b[6], 0.f),
                                    v1.w + fmaxf(acc[i][7] + b[7], 0.f));
            *(float4*)(OUT + (size_t)r * 128 + tx * 4) = o0;
            *(float4*)(OUT + (size_t)r * 128 + 64 + tx * 4) = o1;
        }
    }
}

extern "C" void kernel_launch(void* const* d_in, const int* in_sizes, int n_in,
                              void* d_out, int out_size, void* d_ws, size_t ws_size,
                              hipStream_t stream) {
    const float* variables = (const float*)d_in[0];   // [100000, 128]
    const float* factors   = (const float*)d_in[1];   // [50000, 128]
    const int*   v_to_f    = (const int*)d_in[2];     // [1e6]
    const int*   f_to_v    = (const int*)d_in[3];     // [1e6]
    // d_in[4] edge_attr: forward uses zeros_like -> row 256 of W_msg contributes nothing
    const float* W_msg     = (const float*)d_in[5];   // [257, 128]
    const float* b_msg     = (const float*)d_in[6];   // [128]
    const float* W_comb    = (const float*)d_in[7];   // [256, 128]
    const float* b_comb    = (const float*)d_in[8];   // [128]
    float* out = (float*)d_out;                       // [100000, 128]

    float* u = (float*)d_ws;                 // [NV,128] = variables@W_msg[0:128] + b_msg
    float* w = u + (size_t)NV * 128;         // [NF,128] = factors@W_msg[128:256]
    // ws needed: (NV+NF)*128*4 = 76.8 MB

    // aggr buffer = d_out; zero it (harness poisons with 0xAA)
    zero_f4<<<(NV * 32 + 255) / 256, 256, 0, stream>>>((float4*)out, NV * 32);

    gemm_one<<<(NV + 63) / 64, 256, 0, stream>>>(variables, W_msg, b_msg, u, NV);
    gemm_one<<<(NF + 63) / 64, 256, 0, stream>>>(factors, W_msg + 128 * 128, nullptr, w, NF);

    edge_scatter<<<NE * 32 / 256, 256, 0, stream>>>(u, w, v_to_f, f_to_v, out);

    gemm_final<<<(NV + 63) / 64, 256, 0, stream>>>(variables, W_comb, W_comb + 128 * 128,
                                                   b_comb, out, NV);
}

// Round 2
// 516.223 us; speedup vs baseline: 3.8994x; 3.8994x over previous
//
#include <hip/hip_runtime.h>

#define NV 100000
#define NF 50000
#define NE 1000000
// D = 128 throughout

typedef unsigned short ushort_t;
typedef unsigned int uint_t;

__device__ inline ushort_t f2bf(float x) {
    union { float f; uint_t u; } c; c.f = x;
    uint_t r = c.u + 0x7fffu + ((c.u >> 16) & 1u);   // round-to-nearest-even
    return (ushort_t)(r >> 16);
}
__device__ inline float bf2f(uint_t h) {
    union { uint_t u; float f; } c; c.u = h << 16; return c.f;
}
__device__ inline uint_t pack2(float a, float b) {
    return (uint_t)f2bf(a) | ((uint_t)f2bf(b) << 16);
}

// -------------------- zero int array --------------------
__global__ __launch_bounds__(256) void zero_i(int* __restrict__ p, int n) {
    int i = blockIdx.x * 256 + threadIdx.x;
    if (i < n) p[i] = 0;
}

// -------------------- histogram of v_to_f --------------------
__global__ __launch_bounds__(256) void hist_k(const int* __restrict__ vtf, int* __restrict__ deg) {
    int e = blockIdx.x * 256 + threadIdx.x;
    if (e < NE) atomicAdd(&deg[vtf[e]], 1);
}

// -------------------- scan pass 1: per-1024-chunk sums --------------------
__global__ __launch_bounds__(256) void scan_reduce(const int* __restrict__ deg, int* __restrict__ bsum) {
    __shared__ int s[256];
    int t = threadIdx.x, b = blockIdx.x;
    int base = b * 1024 + t * 4;
    int acc = 0;
#pragma unroll
    for (int j = 0; j < 4; j++) { int i = base + j; if (i < NV) acc += deg[i]; }
    s[t] = acc; __syncthreads();
    for (int off = 128; off > 0; off >>= 1) {
        if (t < off) s[t] += s[t + off];
        __syncthreads();
    }
    if (t == 0) bsum[b] = s[0];
}

// -------------------- scan pass 2: exclusive scan of 98 block sums (1 block) ---------
__global__ __launch_bounds__(128) void scan_mid(int* __restrict__ bsum, int* __restrict__ offs, int nblk) {
    __shared__ int s[128];
    int t = threadIdx.x;
    int val = (t < nblk) ? bsum[t] : 0;
    s[t] = val; __syncthreads();
    for (int off = 1; off < 128; off <<= 1) {
        int x = (t >= off) ? s[t - off] : 0;
        __syncthreads();
        s[t] += x;
        __syncthreads();
    }
    if (t < nblk) bsum[t] = s[t] - val;   // exclusive block offsets
    if (t == 0) offs[NV] = NE;
}

// -------------------- scan pass 3: full exclusive scan; offs + cursor(deg) ----------
__global__ __launch_bounds__(256) void scan_final(int* __restrict__ deg, const int* __restrict__ bsum,
                                                  int* __restrict__ offs) {
    __shared__ int s[256];
    int t = threadIdx.x, b = blockIdx.x;
    int base = b * 1024 + t * 4;
    int v[4];
#pragma unroll
    for (int j = 0; j < 4; j++) { int i = base + j; v[j] = (i < NV) ? deg[i] : 0; }
    int l = v[0] + v[1] + v[2] + v[3];
    s[t] = l; __syncthreads();
    for (int off = 1; off < 256; off <<= 1) {
        int x = (t >= off) ? s[t - off] : 0;
        __syncthreads();
        s[t] += x;
        __syncthreads();
    }
    int run = bsum[b] + s[t] - l;
#pragma unroll
    for (int j = 0; j < 4; j++) {
        int i = base + j;
        if (i < NV) { offs[i] = run; deg[i] = run; }  // deg becomes the scatter cursor
        run += v[j];
    }
}

// -------------------- scatter f-indices into CSR slots (uint16) --------------------
__global__ __launch_bounds__(256) void scatter_k(const int* __restrict__ vtf, const int* __restrict__ ftv,
                                                 int* __restrict__ cursor, ushort_t* __restrict__ sf) {
    int e = blockIdx.x * 256 + threadIdx.x;
    if (e < NE) {
        int v = vtf[e];
        int pos = atomicAdd(&cursor[v], 1);
        sf[pos] = (ushort_t)ftv[e];
    }
}

// -------------------- C[M x 128] = bf16( A[M x 128] @ W[128 x 128] (+ bias) ) -------
__global__ __launch_bounds__(256) void gemm_one(const float* __restrict__ A,
                                                const float* __restrict__ W,
                                                const float* __restrict__ bias,
                                                ushort_t* __restrict__ C, int M) {
    __shared__ float sA[64 * 68];
    __shared__ float sW[64 * 128];
    const int tid = threadIdx.x;
    const int tx = tid & 15;
    const int ty = tid >> 4;
    const int r0 = blockIdx.x * 64;

    float acc[4][8];
#pragma unroll
    for (int i = 0; i < 4; i++)
#pragma unroll
        for (int j = 0; j < 8; j++) acc[i][j] = 0.f;

    for (int kt = 0; kt < 2; ++kt) {
        const int k0 = kt * 64;
#pragma unroll
        for (int i = 0; i < 4; i++) {
            int f = tid + i * 256;
            int r = f >> 4, c4 = f & 15;
            float4 v = make_float4(0.f, 0.f, 0.f, 0.f);
            if (r0 + r < M) v = *(const float4*)(A + (size_t)(r0 + r) * 128 + k0 + c4 * 4);
            *(float4*)(sA + r * 68 + c4 * 4) = v;
        }
#pragma unroll
        for (int i = 0; i < 8; i++) {
            int f = tid + i * 256;
            int r = f >> 5, c4 = f & 31;
            *(float4*)(sW + r * 128 + c4 * 4) = *(const float4*)(W + (size_t)(k0 + r) * 128 + c4 * 4);
        }
        __syncthreads();
#pragma unroll 8
        for (int k = 0; k < 64; k++) {
            float a[4];
#pragma unroll
            for (int i = 0; i < 4; i++) a[i] = sA[(ty * 4 + i) * 68 + k];
            float wv[8];
            *(float4*)&wv[0] = *(const float4*)(sW + k * 128 + tx * 4);
            *(float4*)&wv[4] = *(const float4*)(sW + k * 128 + 64 + tx * 4);
#pragma unroll
            for (int i = 0; i < 4; i++)
#pragma unroll
                for (int j = 0; j < 8; j++) acc[i][j] += a[i] * wv[j];
        }
        __syncthreads();
    }

    float b[8] = {0.f, 0.f, 0.f, 0.f, 0.f, 0.f, 0.f, 0.f};
    if (bias) {
        *(float4*)&b[0] = *(const float4*)(bias + tx * 4);
        *(float4*)&b[4] = *(const float4*)(bias + 64 + tx * 4);
    }
#pragma unroll
    for (int i = 0; i < 4; i++) {
        int r = r0 + ty * 4 + i;
        if (r < M) {
            uint2 o0, o1;
            o0.x = pack2(acc[i][0] + b[0], acc[i][1] + b[1]);
            o0.y = pack2(acc[i][2] + b[2], acc[i][3] + b[3]);
            o1.x = pack2(acc[i][4] + b[4], acc[i][5] + b[5]);
            o1.y = pack2(acc[i][6] + b[6], acc[i][7] + b[7]);
            *(uint2*)(C + (size_t)r * 128 + tx * 4) = o0;
            *(uint2*)(C + (size_t)r * 128 + 64 + tx * 4) = o1;
        }
    }
}

// -------------------- CSR segmented sum: aggr[v] = sum_e relu(u[v]+w[f_e]) ----------
// One wave (64 lanes) per variable; lane owns columns 2l, 2l+1.
__global__ __launch_bounds__(256) void aggregate(const ushort_t* __restrict__ u,
                                                 const ushort_t* __restrict__ w,
                                                 const int* __restrict__ offs,
                                                 const ushort_t* __restrict__ sf,
                                                 float* __restrict__ aggr) {
    int wid = (blockIdx.x * 256 + threadIdx.x) >> 6;   // variable id (wave-uniform)
    int lane = threadIdx.x & 63;
    if (wid >= NV) return;
    uint_t upk = *(const uint_t*)(u + (size_t)wid * 128 + lane * 2);
    float u0 = bf2f(upk & 0xffffu), u1 = bf2f(upk >> 16);
    float a0 = 0.f, a1 = 0.f;
    int i0 = offs[wid], i1 = offs[wid + 1];
    for (int i = i0; i < i1; ++i) {
        int f = sf[i];
        uint_t wpk = *(const uint_t*)(w + (size_t)f * 128 + lane * 2);
        a0 += fmaxf(u0 + bf2f(wpk & 0xffffu), 0.f);
        a1 += fmaxf(u1 + bf2f(wpk >> 16), 0.f);
    }
    *(float2*)(aggr + (size_t)wid * 128 + lane * 2) = make_float2(a0, a1);
}

// -------------------- OUT = V + relu(V@W1 + OUT@W2 + bias), in-place over OUT -------
__global__ __launch_bounds__(256) void gemm_final(const float* __restrict__ V,
                                                  const float* __restrict__ W1,
                                                  const float* __restrict__ W2,
                                                  const float* __restrict__ bias,
                                                  float* __restrict__ OUT, int M) {
    __shared__ float sA[64 * 68];
    __shared__ float sW[64 * 128];
    const int tid = threadIdx.x;
    const int tx = tid & 15;
    const int ty = tid >> 4;
    const int r0 = blockIdx.x * 64;

    float acc[4][8];
#pragma unroll
    for (int i = 0; i < 4; i++)
#pragma unroll
        for (int j = 0; j < 8; j++) acc[i][j] = 0.f;

    for (int kt = 0; kt < 4; ++kt) {
        const float* A = (kt < 2) ? V : OUT;     // OUT holds aggr_m here
        const float* W = (kt < 2) ? W1 : W2;
        const int k0 = (kt & 1) * 64;
#pragma unroll
        for (int i = 0; i < 4; i++) {
            int f = tid + i * 256;
            int r = f >> 4, c4 = f & 15;
            float4 v = make_float4(0.f, 0.f, 0.f, 0.f);
            if (r0 + r < M) v = *(const float4*)(A + (size_t)(r0 + r) * 128 + k0 + c4 * 4);
            *(float4*)(sA + r * 68 + c4 * 4) = v;
        }
#pragma unroll
        for (int i = 0; i < 8; i++) {
            int f = tid + i * 256;
            int r = f >> 5, c4 = f & 31;
            *(float4*)(sW + r * 128 + c4 * 4) = *(const float4*)(W + (size_t)(k0 + r) * 128 + c4 * 4);
        }
        __syncthreads();
#pragma unroll 8
        for (int k = 0; k < 64; k++) {
            float a[4];
#pragma unroll
            for (int i = 0; i < 4; i++) a[i] = sA[(ty * 4 + i) * 68 + k];
            float wv[8];
            *(float4*)&wv[0] = *(const float4*)(sW + k * 128 + tx * 4);
            *(float4*)&wv[4] = *(const float4*)(sW + k * 128 + 64 + tx * 4);
#pragma unroll
            for (int i = 0; i < 4; i++)
#pragma unroll
                for (int j = 0; j < 8; j++) acc[i][j] += a[i] * wv[j];
        }
        __syncthreads();
    }

    float b[8];
    *(float4*)&b[0] = *(const float4*)(bias + tx * 4);
    *(float4*)&b[4] = *(const float4*)(bias + 64 + tx * 4);
#pragma unroll
    for (int i = 0; i < 4; i++) {
        int r = r0 + ty * 4 + i;
        if (r < M) {
            float4 v0 = *(const float4*)(V + (size_t)r * 128 + tx * 4);
            float4 v1 = *(const float4*)(V + (size_t)r * 128 + 64 + tx * 4);
            float4 o0 = make_float4(v0.x + fmaxf(acc[i][0] + b[0], 0.f),
                                    v0.y + fmaxf(acc[i][1] + b[1], 0.f),
                                    v0.z + fmaxf(acc[i][2] + b[2], 0.f),
                                    v0.w + fmaxf(acc[i][3] + b[3], 0.f));
            float4 o1 = make_float4(v1.x + fmaxf(acc[i][4] + b[4], 0.f),
                                    v1.y + fmaxf(acc[i][5] + b[5], 0.f),
                                    v1.z + fmaxf(acc[i][6] + b[6], 0.f),
                                    v1.w + fmaxf(acc[i][7] + b[7], 0.f));
            *(float4*)(OUT + (size_t)r * 128 + tx * 4) = o0;
            *(float4*)(OUT + (size_t)r * 128 + 64 + tx * 4) = o1;
        }
    }
}

extern "C" void kernel_launch(void* const* d_in, const int* in_sizes, int n_in,
                              void* d_out, int out_size, void* d_ws, size_t ws_size,
                              hipStream_t stream) {
    const float* variables = (const float*)d_in[0];   // [100000, 128]
    const float* factors   = (const float*)d_in[1];   // [50000, 128]
    const int*   v_to_f    = (const int*)d_in[2];     // [1e6]
    const int*   f_to_v    = (const int*)d_in[3];     // [1e6]
    // d_in[4] edge_attr: forward uses zeros_like -> last row of W_msg contributes nothing
    const float* W_msg     = (const float*)d_in[5];   // [257, 128]
    const float* b_msg     = (const float*)d_in[6];   // [128]
    const float* W_comb    = (const float*)d_in[7];   // [256, 128]
    const float* b_comb    = (const float*)d_in[8];   // [128]
    float* out = (float*)d_out;                       // [100000, 128]

    // workspace layout (~41.3 MB; round 1 proved ws >= 76.8 MB)
    ushort_t* u    = (ushort_t*)d_ws;                 // [NV*128] bf16
    ushort_t* w    = u + (size_t)NV * 128;            // [NF*128] bf16
    int*      deg  = (int*)(w + (size_t)NF * 128);    // [NV]  (later: scatter cursor)
    int*      offs = deg + NV;                        // [NV+1]
    int*      bsum = offs + NV + 1;                   // [128]
    ushort_t* sf   = (ushort_t*)(bsum + 128);         // [NE] uint16 factor ids

    const int NBLK = (NV + 1023) / 1024;              // 98

    // ---- CSR build ----
    zero_i<<<(NV + 255) / 256, 256, 0, stream>>>(deg, NV);
    hist_k<<<(NE + 255) / 256, 256, 0, stream>>>(v_to_f, deg);
    scan_reduce<<<NBLK, 256, 0, stream>>>(deg, bsum);
    scan_mid<<<1, 128, 0, stream>>>(bsum, offs, NBLK);
    scan_final<<<NBLK, 256, 0, stream>>>(deg, bsum, offs);
    scatter_k<<<(NE + 255) / 256, 256, 0, stream>>>(v_to_f, f_to_v, deg, sf);

    // ---- u = bf16(V @ Wm_top + b_msg), w = bf16(F @ Wm_bot) ----
    gemm_one<<<(NV + 63) / 64, 256, 0, stream>>>(variables, W_msg, b_msg, u, NV);
    gemm_one<<<(NF + 63) / 64, 256, 0, stream>>>(factors, W_msg + 128 * 128, nullptr, w, NF);

    // ---- segmented sum into d_out (writes every row; no zeroing needed) ----
    aggregate<<<(NV * 64) / 256, 256, 0, stream>>>(u, w, offs, sf, out);

    // ---- OUT = V + relu(V@Wc_top + OUT@Wc_bot + b_comb) ----
    gemm_final<<<(NV + 63) / 64, 256, 0, stream>>>(variables, W_comb, W_comb + 128 * 128,
                                                   b_comb, out, NV);
}

// Round 3
// 388.446 us; speedup vs baseline: 5.1821x; 1.3289x over previous
//
#include <hip/hip_runtime.h>

#define NV 100000
#define NF 50000
#define NE 1000000
// D = 128 throughout

typedef unsigned short ushort_t;
typedef unsigned int uint_t;
typedef __attribute__((ext_vector_type(8))) short bf16x8;   // 8 bf16 = 4 VGPRs
typedef __attribute__((ext_vector_type(4))) float f32x4;

__device__ inline ushort_t f2bf(float x) {
    union { float f; uint_t u; } c; c.f = x;
    uint_t r = c.u + 0x7fffu + ((c.u >> 16) & 1u);   // round-to-nearest-even
    return (ushort_t)(r >> 16);
}
__device__ inline float bf2f(uint_t h) {
    union { uint_t u; float f; } c; c.u = h << 16; return c.f;
}
__device__ inline uint_t pack2(float a, float b) {
    return (uint_t)f2bf(a) | ((uint_t)f2bf(b) << 16);
}
__device__ inline bf16x8 pack_frag(const float* p) {
    float4 lo = *(const float4*)p;
    float4 hi = *(const float4*)(p + 4);
    bf16x8 r;
    r[0] = (short)f2bf(lo.x); r[1] = (short)f2bf(lo.y);
    r[2] = (short)f2bf(lo.z); r[3] = (short)f2bf(lo.w);
    r[4] = (short)f2bf(hi.x); r[5] = (short)f2bf(hi.y);
    r[6] = (short)f2bf(hi.z); r[7] = (short)f2bf(hi.w);
    return r;
}

// -------------------- zero int array --------------------
__global__ __launch_bounds__(256) void zero_i(int* __restrict__ p, int n) {
    int i = blockIdx.x * 256 + threadIdx.x;
    if (i < n) p[i] = 0;
}

// -------------------- histogram of v_to_f --------------------
__global__ __launch_bounds__(256) void hist_k(const int* __restrict__ vtf, int* __restrict__ deg) {
    int e = blockIdx.x * 256 + threadIdx.x;
    if (e < NE) atomicAdd(&deg[vtf[e]], 1);
}

// -------------------- scan pass 1: per-1024-chunk sums --------------------
__global__ __launch_bounds__(256) void scan_reduce(const int* __restrict__ deg, int* __restrict__ bsum) {
    __shared__ int s[256];
    int t = threadIdx.x, b = blockIdx.x;
    int base = b * 1024 + t * 4;
    int acc = 0;
#pragma unroll
    for (int j = 0; j < 4; j++) { int i = base + j; if (i < NV) acc += deg[i]; }
    s[t] = acc; __syncthreads();
    for (int off = 128; off > 0; off >>= 1) {
        if (t < off) s[t] += s[t + off];
        __syncthreads();
    }
    if (t == 0) bsum[b] = s[0];
}

// -------------------- scan pass 2: exclusive scan of block sums (1 block) ---------
__global__ __launch_bounds__(128) void scan_mid(int* __restrict__ bsum, int* __restrict__ offs, int nblk) {
    __shared__ int s[128];
    int t = threadIdx.x;
    int val = (t < nblk) ? bsum[t] : 0;
    s[t] = val; __syncthreads();
    for (int off = 1; off < 128; off <<= 1) {
        int x = (t >= off) ? s[t - off] : 0;
        __syncthreads();
        s[t] += x;
        __syncthreads();
    }
    if (t < nblk) bsum[t] = s[t] - val;   // exclusive block offsets
    if (t == 0) offs[NV] = NE;
}

// -------------------- scan pass 3: full exclusive scan; offs + cursor --------------
__global__ __launch_bounds__(256) void scan_final(int* __restrict__ deg, const int* __restrict__ bsum,
                                                  int* __restrict__ offs) {
    __shared__ int s[256];
    int t = threadIdx.x, b = blockIdx.x;
    int base = b * 1024 + t * 4;
    int v[4];
#pragma unroll
    for (int j = 0; j < 4; j++) { int i = base + j; v[j] = (i < NV) ? deg[i] : 0; }
    int l = v[0] + v[1] + v[2] + v[3];
    s[t] = l; __syncthreads();
    for (int off = 1; off < 256; off <<= 1) {
        int x = (t >= off) ? s[t - off] : 0;
        __syncthreads();
        s[t] += x;
        __syncthreads();
    }
    int run = bsum[b] + s[t] - l;
#pragma unroll
    for (int j = 0; j < 4; j++) {
        int i = base + j;
        if (i < NV) { offs[i] = run; deg[i] = run; }  // deg becomes the scatter cursor
        run += v[j];
    }
}

// -------------------- scatter f-indices into CSR slots (uint16) --------------------
__global__ __launch_bounds__(256) void scatter_k(const int* __restrict__ vtf, const int* __restrict__ ftv,
                                                 int* __restrict__ cursor, ushort_t* __restrict__ sf) {
    int e = blockIdx.x * 256 + threadIdx.x;
    if (e < NE) {
        int v = vtf[e];
        int pos = atomicAdd(&cursor[v], 1);
        sf[pos] = (ushort_t)ftv[e];
    }
}

// ---------- prep: rewrite 4 x [128x128] fp32 weight halves into bf16 B-fragment layout ----
// B-frag element (k,n): kc=k>>5, quad=(k&31)>>3, j=k&7, ct=n>>4, lane=(n&15)+16*quad
// storage: frag[mat][ ((kc*8+ct)*64 + lane)*8 + j ]
__global__ __launch_bounds__(256) void prep_w(const float* __restrict__ Wm, const float* __restrict__ Wc,
                                              ushort_t* __restrict__ frag) {
    int t = blockIdx.x * 256 + threadIdx.x;     // 65536 threads
    int mat = t >> 14;
    int idx = t & 16383;
    int k = idx >> 7, n = idx & 127;
    const float* src = (mat < 2) ? (Wm + (size_t)mat * 16384) : (Wc + (size_t)(mat - 2) * 16384);
    float v = src[(size_t)k * 128 + n];
    int kc = k >> 5, kk = k & 31, quad = kk >> 3, j = kk & 7;
    int ct = n >> 4, np = n & 15, lane = np + 16 * quad;
    frag[(size_t)mat * 16384 + (size_t)((kc * 8 + ct) * 64 + lane) * 8 + j] = f2bf(v);
}

// ---------- MFMA GEMM: C_bf16[M x 128] = A_fp32[M x 128] @ Wfrag (+bias) -----------------
// block = 4 waves, wave = 16 rows x 128 cols, no LDS.
__global__ __launch_bounds__(256) void gemm_msg(const float* __restrict__ A,
                                                const ushort_t* __restrict__ wf,
                                                const float* __restrict__ bias,
                                                ushort_t* __restrict__ C, int M) {
    const int wv = threadIdx.x >> 6;
    const int lane = threadIdx.x & 63;
    const int quad = lane >> 4, np = lane & 15;
    const int arow = blockIdx.x * 64 + wv * 16 + np;   // A-frag row for this lane

    f32x4 acc[8];
#pragma unroll
    for (int ct = 0; ct < 8; ct++) acc[ct] = (f32x4){0.f, 0.f, 0.f, 0.f};

#pragma unroll
    for (int kc = 0; kc < 4; kc++) {
        bf16x8 a = {0, 0, 0, 0, 0, 0, 0, 0};
        if (arow < M) a = pack_frag(A + (size_t)arow * 128 + kc * 32 + quad * 8);
        const ushort_t* wp = wf + (size_t)(kc * 8 * 64 + lane) * 8;
#pragma unroll
        for (int ct = 0; ct < 8; ct++) {
            bf16x8 b = *(const bf16x8*)(wp + ct * 512);
            acc[ct] = __builtin_amdgcn_mfma_f32_16x16x32_bf16(a, b, acc[ct], 0, 0, 0);
        }
    }

    const int orow0 = blockIdx.x * 64 + wv * 16 + quad * 4;  // D row = quad*4 + reg
#pragma unroll
    for (int ct = 0; ct < 8; ct++) {
        int col = ct * 16 + np;
        float bb = bias ? bias[col] : 0.f;
#pragma unroll
        for (int r = 0; r < 4; r++) {
            int orow = orow0 + r;
            if (orow < M) C[(size_t)orow * 128 + col] = f2bf(acc[ct][r] + bb);
        }
    }
}

// ---------- CSR segmented sum: aggr_bf16[v] = sum_e relu(u[v]+w[f_e]) --------------------
// One wave per variable; lane owns columns 2l, 2l+1 (packed bf16 pairs). Unroll x2.
__global__ __launch_bounds__(256) void aggregate(const uint_t* __restrict__ u32,
                                                 const uint_t* __restrict__ w32,
                                                 const int* __restrict__ offs,
                                                 const ushort_t* __restrict__ sf,
                                                 uint_t* __restrict__ aggr32) {
    int wid = (blockIdx.x * 256 + threadIdx.x) >> 6;
    int lane = threadIdx.x & 63;
    if (wid >= NV) return;
    uint_t upk = u32[(size_t)wid * 64 + lane];
    float u0 = bf2f(upk & 0xffffu), u1 = bf2f(upk >> 16);
    float a0 = 0.f, a1 = 0.f, b0 = 0.f, b1 = 0.f;
    int i0 = offs[wid], i1 = offs[wid + 1];
    int i = i0;
    for (; i + 2 <= i1; i += 2) {
        int f0 = sf[i], f1 = sf[i + 1];
        uint_t p0 = w32[(size_t)f0 * 64 + lane];
        uint_t p1 = w32[(size_t)f1 * 64 + lane];
        a0 += fmaxf(u0 + bf2f(p0 & 0xffffu), 0.f);
        a1 += fmaxf(u1 + bf2f(p0 >> 16), 0.f);
        b0 += fmaxf(u0 + bf2f(p1 & 0xffffu), 0.f);
        b1 += fmaxf(u1 + bf2f(p1 >> 16), 0.f);
    }
    if (i < i1) {
        uint_t p0 = w32[(size_t)sf[i] * 64 + lane];
        a0 += fmaxf(u0 + bf2f(p0 & 0xffffu), 0.f);
        a1 += fmaxf(u1 + bf2f(p0 >> 16), 0.f);
    }
    aggr32[(size_t)wid * 64 + lane] = pack2(a0 + b0, a1 + b1);
}

// ---------- MFMA final: OUT_fp32 = V + relu(V@Wc_top + aggr@Wc_bot + bias) ---------------
// K = 256: kc 0..3 from V (fp32, convert), kc 4..7 from aggr (bf16 direct).
__global__ __launch_bounds__(256) void gemm_final(const float* __restrict__ V,
                                                  const ushort_t* __restrict__ aggr,
                                                  const ushort_t* __restrict__ wfc,
                                                  const float* __restrict__ bias,
                                                  float* __restrict__ OUT, int M) {
    const int wv = threadIdx.x >> 6;
    const int lane = threadIdx.x & 63;
    const int quad = lane >> 4, np = lane & 15;
    const int arow = blockIdx.x * 64 + wv * 16 + np;

    f32x4 acc[8];
#pragma unroll
    for (int ct = 0; ct < 8; ct++) acc[ct] = (f32x4){0.f, 0.f, 0.f, 0.f};

#pragma unroll
    for (int kc = 0; kc < 8; kc++) {
        bf16x8 a = {0, 0, 0, 0, 0, 0, 0, 0};
        if (arow < M) {
            if (kc < 4) {
                a = pack_frag(V + (size_t)arow * 128 + kc * 32 + quad * 8);
            } else {
                a = *(const bf16x8*)(aggr + (size_t)arow * 128 + (kc - 4) * 32 + quad * 8);
            }
        }
        const ushort_t* wp = wfc + (size_t)(kc >= 4 ? 16384 : 0)
                                 + (size_t)((kc & 3) * 8 * 64 + lane) * 8;
#pragma unroll
        for (int ct = 0; ct < 8; ct++) {
            bf16x8 b = *(const bf16x8*)(wp + ct * 512);
            acc[ct] = __builtin_amdgcn_mfma_f32_16x16x32_bf16(a, b, acc[ct], 0, 0, 0);
        }
    }

    const int orow0 = blockIdx.x * 64 + wv * 16 + quad * 4;
#pragma unroll
    for (int ct = 0; ct < 8; ct++) {
        int col = ct * 16 + np;
        float bb = bias[col];
#pragma unroll
        for (int r = 0; r < 4; r++) {
            int orow = orow0 + r;
            if (orow < M) {
                float v = V[(size_t)orow * 128 + col];
                OUT[(size_t)orow * 128 + col] = v + fmaxf(acc[ct][r] + bb, 0.f);
            }
        }
    }
}

extern "C" void kernel_launch(void* const* d_in, const int* in_sizes, int n_in,
                              void* d_out, int out_size, void* d_ws, size_t ws_size,
                              hipStream_t stream) {
    const float* variables = (const float*)d_in[0];   // [100000, 128]
    const float* factors   = (const float*)d_in[1];   // [50000, 128]
    const int*   v_to_f    = (const int*)d_in[2];     // [1e6]
    const int*   f_to_v    = (const int*)d_in[3];     // [1e6]
    // d_in[4] edge_attr: forward uses zeros_like -> last row of W_msg contributes nothing
    const float* W_msg     = (const float*)d_in[5];   // [257, 128]
    const float* b_msg     = (const float*)d_in[6];   // [128]
    const float* W_comb    = (const float*)d_in[7];   // [256, 128]
    const float* b_comb    = (const float*)d_in[8];   // [128]
    float* out = (float*)d_out;                       // [100000, 128]

    // workspace layout (~67 MB; round 1 proved ws >= 76.8 MB)
    ushort_t* wfrag = (ushort_t*)d_ws;                 // 4 x 16384 bf16 = 128 KB
    ushort_t* u     = wfrag + 4 * 16384;               // [NV*128] bf16
    ushort_t* w     = u + (size_t)NV * 128;            // [NF*128] bf16
    ushort_t* aggr  = w + (size_t)NF * 128;            // [NV*128] bf16
    ushort_t* sf    = aggr + (size_t)NV * 128;         // [NE] uint16 factor ids
    int*      deg   = (int*)(sf + NE);                 // [NV]
    int*      offs  = deg + NV;                        // [NV+1]
    int*      bsum  = offs + NV + 1;                   // [128]

    const int NBLK = (NV + 1023) / 1024;               // 98

    // ---- weight fragments (independent of everything) ----
    prep_w<<<256, 256, 0, stream>>>(W_msg, W_comb, wfrag);

    // ---- CSR build ----
    zero_i<<<(NV + 255) / 256, 256, 0, stream>>>(deg, NV);
    hist_k<<<(NE + 255) / 256, 256, 0, stream>>>(v_to_f, deg);
    scan_reduce<<<NBLK, 256, 0, stream>>>(deg, bsum);
    scan_mid<<<1, 128, 0, stream>>>(bsum, offs, NBLK);
    scan_final<<<NBLK, 256, 0, stream>>>(deg, bsum, offs);
    scatter_k<<<(NE + 255) / 256, 256, 0, stream>>>(v_to_f, f_to_v, deg, sf);

    // ---- u = bf16(V @ Wm_top + b_msg), w = bf16(F @ Wm_bot) ----
    gemm_msg<<<(NV + 63) / 64, 256, 0, stream>>>(variables, wfrag, b_msg, u, NV);
    gemm_msg<<<(NF + 63) / 64, 256, 0, stream>>>(factors, wfrag + 16384, nullptr, w, NF);

    // ---- segmented sum -> aggr (bf16) ----
    aggregate<<<(NV * 64) / 256, 256, 0, stream>>>((const uint_t*)u, (const uint_t*)w,
                                                   offs, sf, (uint_t*)aggr);

    // ---- OUT = V + relu(V@Wc_top + aggr@Wc_bot + b_comb) ----
    gemm_final<<<(NV + 63) / 64, 256, 0, stream>>>(variables, aggr, wfrag + 2 * 16384,
                                                   b_comb, out, NV);
}